// Round 4
// baseline (589.889 us; speedup 1.0000x reference)
//
#include <hip/hip_runtime.h>
#include <math.h>

#define E_ 4
#define B_ 128
#define Q_ 900
#define C_ 256
#define H_ 16
#define QC (Q_ * C_)   // 230400

typedef float f4_t __attribute__((ext_vector_type(4)));

// ---------------------------------------------------------------------------
// Kernel 1 (fused probs + gate): one block of 256 threads per sample b.
// Wave w (=expert e) reduces mean_q logits[e,b,q,0]; thread 0 then runs the
// gating MLP + softmax + top-2 + renorm and writes all small outputs.
// Gating for b depends ONLY on probs[b,:], so this fuses cleanly per-b.
// ---------------------------------------------------------------------------
__global__ __launch_bounds__(256) void probs_gate_kernel(
        const float* __restrict__ logits,   // [E,B,Q,C]
        const float* __restrict__ W1,       // [E,H]
        const float* __restrict__ b1,       // [H]
        const float* __restrict__ W2,       // [H,E]
        const float* __restrict__ b2,       // [E]
        float* __restrict__ out_probs,      // [B,E]
        float* __restrict__ out_norm_w,     // [B,E]
        float* __restrict__ out_final,      // [B]
        float* __restrict__ out_topidx,     // [B,2] (as float)
        float* __restrict__ ws_w,           // [2,B]
        int*   __restrict__ ws_i) {         // [2,B]
    __shared__ float red[E_];
    int b = blockIdx.x;
    int t = threadIdx.x;
    int e = t >> 6;            // wave index = expert index
    int lane = t & 63;

    // regular (cacheable) loads: these lines get re-read by combine via LLC
    const float* base = logits + (size_t)(e * B_ + b) * QC;
    float s = 0.f;
    #pragma unroll
    for (int q = lane; q < Q_; q += 64)    // 15 strided loads (last partial)
        s += base[(size_t)q * C_];

    #pragma unroll
    for (int off = 32; off > 0; off >>= 1)
        s += __shfl_down(s, off, 64);

    if (lane == 0) red[e] = s;
    __syncthreads();

    if (t == 0) {
        float p[E_];
        #pragma unroll
        for (int k = 0; k < E_; k++) {
            float m = red[k] * (1.0f / (float)Q_);
            p[k] = 1.0f / (1.0f + expf(-m));
            out_probs[b * E_ + k] = p[k];
        }

        // h = relu(p @ W1 + b1)
        float h[H_];
        #pragma unroll
        for (int j = 0; j < H_; j++) {
            float a = b1[j];
            #pragma unroll
            for (int k = 0; k < E_; k++) a += p[k] * W1[k * H_ + j];
            h[j] = fmaxf(a, 0.f);
        }

        // logits = h @ W2 + b2 ; softmax
        float lg[E_], mx = -1e30f;
        #pragma unroll
        for (int k = 0; k < E_; k++) {
            float a = b2[k];
            #pragma unroll
            for (int j = 0; j < H_; j++) a += h[j] * W2[j * E_ + k];
            lg[k] = a;
            mx = fmaxf(mx, a);
        }
        float w[E_], sum = 0.f;
        #pragma unroll
        for (int k = 0; k < E_; k++) { w[k] = expf(lg[k] - mx); sum += w[k]; }
        float inv = 1.0f / sum;
        #pragma unroll
        for (int k = 0; k < E_; k++) w[k] *= inv;

        // top-2 (strict > keeps lowest index on ties, matching jax.lax.top_k)
        int i0 = 0;
        #pragma unroll
        for (int k = 1; k < E_; k++) if (w[k] > w[i0]) i0 = k;
        int i1 = -1;
        #pragma unroll
        for (int k = 0; k < E_; k++)
            if (k != i0 && (i1 < 0 || w[k] > w[i1])) i1 = k;

        float s2  = w[i0] + w[i1] + 1e-8f;
        float nw0 = w[i0] / s2;
        float nw1 = w[i1] / s2;

        #pragma unroll
        for (int k = 0; k < E_; k++) out_norm_w[b * E_ + k] = 0.f;
        out_norm_w[b * E_ + i0] = nw0;
        out_norm_w[b * E_ + i1] = nw1;

        out_final[b] = nw0 * p[i0] + nw1 * p[i1];
        out_topidx[b * 2 + 0] = (float)i0;
        out_topidx[b * 2 + 1] = (float)i1;

        ws_w[b]      = nw0;
        ws_w[B_ + b] = nw1;
        ws_i[b]      = i0;
        ws_i[B_ + b] = i1;
    }
}

// ---------------------------------------------------------------------------
// Kernel 2: combined[b,q,c] = nw0*logits[i0,b,:,:] + nw1*logits[i1,b,:,:]
// Grid (75, B), block 256, 3 float4 per thread (75*256*3 = 57600 = QC/4).
// Touch-once streaming -> nontemporal; 3 independent load pairs for ILP.
// ---------------------------------------------------------------------------
__global__ __launch_bounds__(256) void combine_kernel(
        const float* __restrict__ logits,
        const float* __restrict__ ws_w,
        const int*   __restrict__ ws_i,
        float* __restrict__ out) {
    int b  = blockIdx.y;
    float w0 = ws_w[b];
    float w1 = ws_w[B_ + b];
    int   i0 = ws_i[b];
    int   i1 = ws_i[B_ + b];

    const f4_t* s0 = (const f4_t*)(logits + (size_t)(i0 * B_ + b) * QC);
    const f4_t* s1 = (const f4_t*)(logits + (size_t)(i1 * B_ + b) * QC);
    f4_t*       o  = (f4_t*)(out + (size_t)b * QC);

    int idx = blockIdx.x * 768 + threadIdx.x;   // 3 chunks of 256
    f4_t a0 = __builtin_nontemporal_load(s0 + idx);
    f4_t c0 = __builtin_nontemporal_load(s1 + idx);
    f4_t a1 = __builtin_nontemporal_load(s0 + idx + 256);
    f4_t c1 = __builtin_nontemporal_load(s1 + idx + 256);
    f4_t a2 = __builtin_nontemporal_load(s0 + idx + 512);
    f4_t c2 = __builtin_nontemporal_load(s1 + idx + 512);
    __builtin_nontemporal_store(w0 * a0 + w1 * c0, o + idx);
    __builtin_nontemporal_store(w0 * a1 + w1 * c1, o + idx + 256);
    __builtin_nontemporal_store(w0 * a2 + w1 * c2, o + idx + 512);
}

// ---------------------------------------------------------------------------
extern "C" void kernel_launch(void* const* d_in, const int* in_sizes, int n_in,
                              void* d_out, int out_size, void* d_ws, size_t ws_size,
                              hipStream_t stream) {
    const float* logits = (const float*)d_in[0];  // [E,B,Q,C]
    const float* W1     = (const float*)d_in[1];  // [E,H]
    const float* b1     = (const float*)d_in[2];  // [H]
    const float* W2     = (const float*)d_in[3];  // [H,E]
    const float* b2     = (const float*)d_in[4];  // [E]

    float* out          = (float*)d_out;
    float* out_combined = out;                            // B*Q*C
    float* out_final    = out_combined + (size_t)B_ * QC; // B
    float* out_norm_w   = out_final + B_;                 // B*E
    float* out_probs    = out_norm_w + B_ * E_;           // B*E
    float* out_topidx   = out_probs + B_ * E_;            // B*2

    float* ws_w = (float*)d_ws;           // 2*B floats
    int*   ws_i = (int*)(ws_w + 2 * B_);  // 2*B ints

    probs_gate_kernel<<<B_, 256, 0, stream>>>(logits, W1, b1, W2, b2,
                                              out_probs, out_norm_w, out_final,
                                              out_topidx, ws_w, ws_i);
    combine_kernel<<<dim3(75, B_), 256, 0, stream>>>(logits, ws_w, ws_i,
                                                     out_combined);
}